// Round 1
// baseline (28.845 us; speedup 1.0000x reference)
//
#include <hip/hip_runtime.h>
#include <hip/hip_bf16.h>

// InvariantPolynomial: out = sum_e xl[oi[e]] * xr[e] * f(|pos_e|)
// f(d) tabulated (8192-entry LUT over [0,5], linear interp), since the whole
// MLP path depends only on d. sh[:, :1] == 1 identically (l=0 component).
//
// ws layout: [0, 32768) float LUT; [32768, 32768+2048*8) double block partials.
// Requires ws_size >= 49152 bytes.

#define TN 8192          // LUT entries
#define DMAX 5.0f        // LUT range; f(d) == 0 (fp32) for d >= 5 (gaussian underflow)
#define NBLK 2048        // main-kernel blocks / partials

// 1/sqrt(E[silu(z)^2]), z~N(0,1). Two independent quadratures agree: 1.676558 +- 2e-4.
// Tolerance is ~2% of |out|, sensitivity is linear in this constant -> safe.
__device__ __constant__ float kSiluCst = 1.6765581f;

__global__ __launch_bounds__(256) void build_lut_kernel(
    const float* __restrict__ W1, const float* __restrict__ W2,
    float* __restrict__ table)
{
    // 32 lanes per LUT entry: lane k in [0,30) computes hidden unit k.
    int t = blockIdx.x * 256 + threadIdx.x;
    int entry = t >> 5;
    int k = t & 31;
    int kk = (k < 30) ? k : 29;              // clamp for safe loads; zeroed below

    float d  = (float)entry * (DMAX / (float)TN);
    float t6 = 6.0f * d;                      // centers at t6 = 1..20, width 1 (step=1/6)
    const float w1scale = 1.0f / (1.12f * sqrtf(20.0f)); // emb/1.12 and W1/sqrt(20) folded

    float a = 0.0f;
    #pragma unroll
    for (int j = 0; j < 20; ++j) {
        float df = t6 - (float)(j + 1);
        float e  = __expf(-df * df);
        a = fmaf(e * w1scale, W1[j * 30 + kk], a);
    }
    // silu
    float s = a / (1.0f + __expf(-a));

    float w2s = 0.0f;
    #pragma unroll
    for (int c = 0; c < 5; ++c) w2s += W2[kk * 5 + c];

    float contrib = (k < 30) ? s * w2s * (kSiluCst / sqrtf(30.0f)) : 0.0f;

    // butterfly reduce within each 32-lane group
    #pragma unroll
    for (int m = 16; m > 0; m >>= 1) contrib += __shfl_xor(contrib, m, 32);

    if (k == 0 && entry < TN) table[entry] = contrib;
}

__global__ __launch_bounds__(256) void edge_sum_kernel(
    const float* __restrict__ pos, const float* __restrict__ xr,
    const float* __restrict__ xl, const int* __restrict__ oi,
    const float* __restrict__ table, double* __restrict__ partials, int E)
{
    __shared__ float lut[TN];
    __shared__ double swv[4];

    // stage LUT into LDS (vectorized)
    {
        const float4* t4 = (const float4*)table;
        float4* l4 = (float4*)lut;
        for (int i = threadIdx.x; i < TN / 4; i += 256) l4[i] = t4[i];
    }
    __syncthreads();

    const float scale = (float)TN / DMAX;
    double acc = 0.0;
    int stride = gridDim.x * blockDim.x;
    for (int e = blockIdx.x * blockDim.x + threadIdx.x; e < E; e += stride) {
        float px = pos[3 * e + 0];
        float py = pos[3 * e + 1];
        float pz = pos[3 * e + 2];
        float d  = sqrtf(fmaf(px, px, fmaf(py, py, pz * pz)));
        float u  = fminf(d * scale, (float)(TN - 1) - 1e-3f); // clamp: f ~ 0 out there
        int   i0 = (int)u;
        float fr = u - (float)i0;
        float f0 = lut[i0];
        float f1 = lut[i0 + 1];
        float f  = fmaf(fr, f1 - f0, f0);
        float v  = f * xr[e] * xl[oi[e]];
        acc += (double)v;
    }

    // deterministic block reduction (wave shfl + LDS across 4 waves)
    #pragma unroll
    for (int off = 32; off > 0; off >>= 1) acc += __shfl_down(acc, off);
    int lane = threadIdx.x & 63, wv = threadIdx.x >> 6;
    if (lane == 0) swv[wv] = acc;
    __syncthreads();
    if (threadIdx.x == 0)
        partials[blockIdx.x] = (swv[0] + swv[1]) + (swv[2] + swv[3]);
}

__global__ __launch_bounds__(256) void final_reduce_kernel(
    const double* __restrict__ partials, int n, float* __restrict__ out)
{
    __shared__ double sm[256];
    double a = 0.0;
    for (int i = threadIdx.x; i < n; i += 256) a += partials[i];
    sm[threadIdx.x] = a;
    __syncthreads();
    #pragma unroll
    for (int s = 128; s > 0; s >>= 1) {
        if (threadIdx.x < (unsigned)s) sm[threadIdx.x] += sm[threadIdx.x + s];
        __syncthreads();
    }
    if (threadIdx.x == 0) out[0] = (float)sm[0];
}

extern "C" void kernel_launch(void* const* d_in, const int* in_sizes, int n_in,
                              void* d_out, int out_size, void* d_ws, size_t ws_size,
                              hipStream_t stream) {
    const float* pos = (const float*)d_in[0];   // [E,3]
    const float* xr  = (const float*)d_in[1];   // [E,1]
    const float* xl  = (const float*)d_in[2];   // [N,1]
    const float* W1  = (const float*)d_in[3];   // [20,30]
    const float* W2  = (const float*)d_in[4];   // [30,5]
    const int*   oi  = (const int*)d_in[5];     // [E]
    float* out = (float*)d_out;

    int E = in_sizes[1];

    float*  table    = (float*)d_ws;
    double* partials = (double*)((char*)d_ws + (size_t)TN * sizeof(float));

    hipLaunchKernelGGL(build_lut_kernel, dim3((TN * 32) / 256), dim3(256), 0, stream,
                       W1, W2, table);
    hipLaunchKernelGGL(edge_sum_kernel, dim3(NBLK), dim3(256), 0, stream,
                       pos, xr, xl, oi, table, partials, E);
    hipLaunchKernelGGL(final_reduce_kernel, dim3(1), dim3(256), 0, stream,
                       partials, NBLK, out);
}